// Round 2
// baseline (909.470 us; speedup 1.0000x reference)
//
#include <hip/hip_runtime.h>

// MultiHeadDirectionalAttention on MI355X (gfx950).
// Facts exploited:
//  - direction_signal input is unused by the reference.
//  - The direction-bias MLP adds a per-(b,h,q) constant over the key axis ->
//    cancels exactly in softmax -> ds1/ds2 path skipped entirely.
//  - I/O dtype: float32 (reference dtype; round-1 NaN proved inputs are f32 —
//    reading f32 as bf16 halves produces bf16-NaN bit patterns at ~0.4%/elem).
//  - f32 -> f16 conversion for MFMA; Q pre-scaled by 1/8 keeps logit error
//    ~6e-4, far under the 3.9e-3 threshold.
// Workspace: 48 MB.

typedef unsigned short u16;
typedef unsigned int   u32;
typedef _Float16       f16;
typedef f16   half8   __attribute__((ext_vector_type(8)));
typedef float floatx4 __attribute__((ext_vector_type(4)));
typedef u32   u32x4   __attribute__((ext_vector_type(4)));

union V8 { u16 u[8]; u32x4 v; };

__device__ __forceinline__ u16 f16_bits(float f){
    union { f16 h; u16 u; } x; x.h = (f16)f; return x.u;
}

// ---------------------------------------------------------------------------
// 64x64-tile transpose, output = f16 bits (u16). TI=float converts f32->f16;
// TI=u16 passes f16 bits through.
// in: logical (R x C), row stride irs; out: (C x R), row stride ors.
// blockIdx.z batches: b = z/zdiv, h = z%zdiv with separate base strides.
// ---------------------------------------------------------------------------
template<typename TI>
__global__ __launch_bounds__(256) void transpose_k(
    const TI* __restrict__ in, u16* __restrict__ out,
    long irs, long ors, int zdiv, long ibs0, long ibs1, long obs0, long obs1)
{
    __shared__ u16 tile[64][72];
    int z = blockIdx.z;
    const TI* ip = in  + (long)(z / zdiv) * ibs0 + (long)(z % zdiv) * ibs1;
    u16*      op = out + (long)(z / zdiv) * obs0 + (long)(z % zdiv) * obs1;
    long r0 = (long)blockIdx.y * 64, c0 = (long)blockIdx.x * 64;
    int t = threadIdx.x;
    int r = t >> 2, cs = (t & 3) * 16;
#pragma unroll
    for (int j = 0; j < 16; j++){
        TI v = ip[(r0 + r) * irs + c0 + cs + j];
        if (sizeof(TI) == 4) tile[r][cs + j] = f16_bits((float)v);
        else                 tile[r][cs + j] = (u16)v;
    }
    __syncthreads();
#pragma unroll
    for (int j = 0; j < 16; j++){
        op[(c0 + r) * ors + r0 + cs + j] = tile[cs + j][r];
    }
}

// ---------------------------------------------------------------------------
// C(M,N) = A(M,K) * BT(N,K)^T + bias(N), 64x64 tile, f16 MFMA.
// A_F32: A is f32 (converted to f16 during LDS staging); else f16 bits.
// OUT_F32: emit f32; else f16 bits. out_scale applied after bias.
// ---------------------------------------------------------------------------
template<bool A_F32, bool OUT_F32>
__global__ __launch_bounds__(256) void gemm_bt(
    const void* __restrict__ Av, const u16* __restrict__ BT,
    const float* __restrict__ bias, void* __restrict__ Cv,
    int M, int N, int K, float out_scale)
{
    __shared__ u16 Alds[64][40];
    __shared__ u16 Blds[64][40];
    int m0 = blockIdx.y * 64, n0 = blockIdx.x * 64;
    int t = threadIdx.x, w = t >> 6, lane = t & 63, quad = lane >> 4, l16 = lane & 15;
    int wm = (w >> 1) * 32, wn = (w & 1) * 32;
    const floatx4 zero4 = {0.f, 0.f, 0.f, 0.f};
    floatx4 acc[2][2];
#pragma unroll
    for (int i = 0; i < 2; i++)
#pragma unroll
        for (int j = 0; j < 2; j++) acc[i][j] = zero4;

    int srow = t >> 2, scol = (t & 3) * 8;
    const float* Apf = (const float*)Av + (long)(m0 + srow) * K + scol;
    const u16*   Aph = (const u16*)Av   + (long)(m0 + srow) * K + scol;
    const u16*   Bp  = BT + (long)(n0 + srow) * K + scol;

    for (int k0 = 0; k0 < K; k0 += 32){
        __syncthreads();
        V8 va, vb;
        if (A_F32){
            floatx4 a0 = *(const floatx4*)(Apf + k0);
            floatx4 a1 = *(const floatx4*)(Apf + k0 + 4);
#pragma unroll
            for (int j = 0; j < 4; j++){
                va.u[j]     = f16_bits(a0[j]);
                va.u[4 + j] = f16_bits(a1[j]);
            }
        } else {
            va.v = *(const u32x4*)(Aph + k0);
        }
        vb.v = *(const u32x4*)(Bp + k0);
        *(u32x4*)&Alds[srow][scol] = va.v;
        *(u32x4*)&Blds[srow][scol] = vb.v;
        __syncthreads();
        half8 a0 = *(const half8*)&Alds[wm + l16][quad * 8];
        half8 a1 = *(const half8*)&Alds[wm + 16 + l16][quad * 8];
        half8 b0 = *(const half8*)&Blds[wn + l16][quad * 8];
        half8 b1 = *(const half8*)&Blds[wn + 16 + l16][quad * 8];
        acc[0][0] = __builtin_amdgcn_mfma_f32_16x16x32_f16(a0, b0, acc[0][0], 0, 0, 0);
        acc[0][1] = __builtin_amdgcn_mfma_f32_16x16x32_f16(a0, b1, acc[0][1], 0, 0, 0);
        acc[1][0] = __builtin_amdgcn_mfma_f32_16x16x32_f16(a1, b0, acc[1][0], 0, 0, 0);
        acc[1][1] = __builtin_amdgcn_mfma_f32_16x16x32_f16(a1, b1, acc[1][1], 0, 0, 0);
    }

#pragma unroll
    for (int mi = 0; mi < 2; mi++)
#pragma unroll
        for (int ni = 0; ni < 2; ni++){
            int n = n0 + wn + ni * 16 + l16;
            float bv = bias[n];
#pragma unroll
            for (int r = 0; r < 4; r++){
                int m = m0 + wm + mi * 16 + quad * 4 + r;
                float v = (acc[mi][ni][r] + bv) * out_scale;
                if (OUT_F32) ((float*)Cv)[(long)m * N + n] = v;
                else         ((u16*)Cv)[(long)m * N + n]   = f16_bits(v);
            }
        }
}

// ---------------------------------------------------------------------------
// Fused attention. Q already pre-scaled by 1/sqrt(hd).
// Q,K: (B*2048, 1024) f16, head h at column h*64.  VT: (B,16,64,2048) f16.
// Block = 64 queries of one (b,h); 4 waves x 16 queries. Two passes over keys
// (chunk 64): pass A online max/sumexp; pass B recompute -> attention probs
// written f32 straight from accumulator regs (64B-coalesced per quad) + f16
// copy into LDS (A-operand layout) for the PV MFMA accumulation.
// ---------------------------------------------------------------------------
#define S_LEN 2048
#define NH 16
#define HD 64

__global__ __launch_bounds__(256) void attn_k(
    const u16* __restrict__ Q, const u16* __restrict__ K,
    const u16* __restrict__ VT, float* __restrict__ attn,
    u16* __restrict__ ctx)
{
    __shared__ u16 Klds [64][72];
    __shared__ u16 Vtlds[64][72];
    __shared__ u16 Plds [64][72];
    int bx = blockIdx.x;
    int qb = bx & 31, h = (bx >> 5) & 15, b = bx >> 9;
    int q0 = qb * 64;
    int t = threadIdx.x, w = t >> 6, lane = t & 63, quad = lane >> 4, l16 = lane & 15;
    const u16* Qp  = Q + (long)b * S_LEN * 1024 + h * HD;
    const u16* Kp  = K + (long)b * S_LEN * 1024 + h * HD;
    const u16* VTp = VT + ((long)(b * NH + h)) * HD * S_LEN;

    int qrow = q0 + w * 16 + l16;
    half8 qf0 = *(const half8*)(Qp + (long)qrow * 1024 + quad * 8);
    half8 qf1 = *(const half8*)(Qp + (long)qrow * 1024 + 32 + quad * 8);

    int srow = t >> 2, sseg = (t & 3) * 16;
    float m[4], l[4];
#pragma unroll
    for (int r = 0; r < 4; r++){ m[r] = -1e30f; l[r] = 0.f; }
    const floatx4 zero4 = {0.f, 0.f, 0.f, 0.f};

    // ---- pass A: softmax statistics ----
    for (int k0 = 0; k0 < S_LEN; k0 += 64){
        __syncthreads();
        *(u32x4*)&Klds[srow][sseg]     = *(const u32x4*)(Kp + (long)(k0 + srow) * 1024 + sseg);
        *(u32x4*)&Klds[srow][sseg + 8] = *(const u32x4*)(Kp + (long)(k0 + srow) * 1024 + sseg + 8);
        __syncthreads();
        floatx4 sc[4];
#pragma unroll
        for (int kt = 0; kt < 4; kt++){
            sc[kt] = zero4;
            half8 kf0 = *(const half8*)&Klds[kt * 16 + l16][quad * 8];
            half8 kf1 = *(const half8*)&Klds[kt * 16 + l16][32 + quad * 8];
            sc[kt] = __builtin_amdgcn_mfma_f32_16x16x32_f16(qf0, kf0, sc[kt], 0, 0, 0);
            sc[kt] = __builtin_amdgcn_mfma_f32_16x16x32_f16(qf1, kf1, sc[kt], 0, 0, 0);
        }
#pragma unroll
        for (int r = 0; r < 4; r++){
            float s0 = sc[0][r], s1 = sc[1][r], s2 = sc[2][r], s3 = sc[3][r];
            float mx = fmaxf(fmaxf(s0, s1), fmaxf(s2, s3));
#pragma unroll
            for (int off = 1; off < 16; off <<= 1) mx = fmaxf(mx, __shfl_xor(mx, off));
            float nm = fmaxf(m[r], mx);
            float ps = __expf(s0 - nm) + __expf(s1 - nm) + __expf(s2 - nm) + __expf(s3 - nm);
#pragma unroll
            for (int off = 1; off < 16; off <<= 1) ps += __shfl_xor(ps, off);
            l[r] = l[r] * __expf(m[r] - nm) + ps;
            m[r] = nm;
        }
    }

    float linv[4];
#pragma unroll
    for (int r = 0; r < 4; r++) linv[r] = 1.f / l[r];
    floatx4 ctxa[4];
#pragma unroll
    for (int dt = 0; dt < 4; dt++) ctxa[dt] = zero4;

    // attention row base for this lane's quad (rows quad*4 + r)
    long arow0 = ((long)(b * NH + h) * S_LEN + (q0 + w * 16 + quad * 4)) * S_LEN;

    // ---- pass B: probabilities + PV ----
    for (int k0 = 0; k0 < S_LEN; k0 += 64){
        __syncthreads();
        *(u32x4*)&Klds [srow][sseg]     = *(const u32x4*)(Kp  + (long)(k0 + srow) * 1024 + sseg);
        *(u32x4*)&Klds [srow][sseg + 8] = *(const u32x4*)(Kp  + (long)(k0 + srow) * 1024 + sseg + 8);
        *(u32x4*)&Vtlds[srow][sseg]     = *(const u32x4*)(VTp + (long)srow * S_LEN + k0 + sseg);
        *(u32x4*)&Vtlds[srow][sseg + 8] = *(const u32x4*)(VTp + (long)srow * S_LEN + k0 + sseg + 8);
        __syncthreads();
        floatx4 sc[4];
#pragma unroll
        for (int kt = 0; kt < 4; kt++){
            sc[kt] = zero4;
            half8 kf0 = *(const half8*)&Klds[kt * 16 + l16][quad * 8];
            half8 kf1 = *(const half8*)&Klds[kt * 16 + l16][32 + quad * 8];
            sc[kt] = __builtin_amdgcn_mfma_f32_16x16x32_f16(qf0, kf0, sc[kt], 0, 0, 0);
            sc[kt] = __builtin_amdgcn_mfma_f32_16x16x32_f16(qf1, kf1, sc[kt], 0, 0, 0);
        }
#pragma unroll
        for (int kt = 0; kt < 4; kt++)
#pragma unroll
            for (int r = 0; r < 4; r++){
                float p = __expf(sc[kt][r] - m[r]) * linv[r];
                attn[arow0 + (long)r * S_LEN + k0 + kt * 16 + l16] = p;
                Plds[w * 16 + quad * 4 + r][kt * 16 + l16] = f16_bits(p);
            }
        __syncthreads();
        // PV: A = P (A-layout via Plds), B = V (BT-layout via Vtlds)
#pragma unroll
        for (int kk = 0; kk < 2; kk++){
            half8 pf = *(const half8*)&Plds[w * 16 + l16][kk * 32 + quad * 8];
#pragma unroll
            for (int dt = 0; dt < 4; dt++){
                half8 vf = *(const half8*)&Vtlds[dt * 16 + l16][kk * 32 + quad * 8];
                ctxa[dt] = __builtin_amdgcn_mfma_f32_16x16x32_f16(pf, vf, ctxa[dt], 0, 0, 0);
            }
        }
    }

    // ---- context epilogue: f16 out to workspace, coalesced via LDS ----
    __syncthreads();
#pragma unroll
    for (int dt = 0; dt < 4; dt++)
#pragma unroll
        for (int r = 0; r < 4; r++)
            Plds[w * 16 + quad * 4 + r][dt * 16 + l16] = f16_bits(ctxa[dt][r]);
    __syncthreads();
    {
        V8 o0, o1;
#pragma unroll
        for (int j = 0; j < 8; j++){
            o0.u[j] = Plds[srow][sseg + j];
            o1.u[j] = Plds[srow][sseg + 8 + j];
        }
        long cbase = ((long)b * S_LEN + q0 + srow) * 1024 + h * HD + sseg;
        *(u32x4*)(ctx + cbase)     = o0.v;
        *(u32x4*)(ctx + cbase + 8) = o1.v;
    }
}

// ---------------------------------------------------------------------------
extern "C" void kernel_launch(void* const* d_in, const int* in_sizes, int n_in,
                              void* d_out, int out_size, void* d_ws, size_t ws_size,
                              hipStream_t stream)
{
    (void)in_sizes; (void)n_in; (void)out_size; (void)ws_size;
    const float* query  = (const float*)d_in[0];
    const float* key_in = (const float*)d_in[1];
    const float* value  = (const float*)d_in[2];
    // d_in[3] direction_signal: unused by the reference
    const float* Wq_w = (const float*)d_in[4];  const float* Wq_b = (const float*)d_in[5];
    const float* Wk_w = (const float*)d_in[6];  const float* Wk_b = (const float*)d_in[7];
    const float* Wv_w = (const float*)d_in[8];  const float* Wv_b = (const float*)d_in[9];
    // d_in[10..13] ds1/ds2: bias is constant over keys -> cancels in softmax
    const float* fo_w = (const float*)d_in[14]; const float* fo_b = (const float*)d_in[15];

    float* out  = (float*)d_out;        // (B,S,H) f32
    float* attn = out + 4194304L;       // (B,nh,S,S) f32

    u16* ws  = (u16*)d_ws;
    u16* WqT = ws;                      // 1024x1024 f16 each
    u16* WkT = WqT + 1048576;
    u16* WvT = WkT + 1048576;
    u16* foT = WvT + 1048576;
    u16* Qm  = foT + 1048576;           // 4096x1024 f16 each
    u16* Km  = Qm  + 4194304;
    u16* Vm  = Km  + 4194304;
    u16* VTm = Vm  + 4194304;           // (B,16,64,2048) f16
    u16* CTX = VTm + 4194304;           // 4096x1024 f16
    // total: 25,165,824 u16 = 48 MB of workspace

    dim3 blk(256);
    // weight transposes (f32 -> f16, BT layout)
    transpose_k<float><<<dim3(16,16,1), blk, 0, stream>>>(Wq_w, WqT, 1024,1024, 1, 0,0, 0,0);
    transpose_k<float><<<dim3(16,16,1), blk, 0, stream>>>(Wk_w, WkT, 1024,1024, 1, 0,0, 0,0);
    transpose_k<float><<<dim3(16,16,1), blk, 0, stream>>>(Wv_w, WvT, 1024,1024, 1, 0,0, 0,0);
    transpose_k<float><<<dim3(16,16,1), blk, 0, stream>>>(fo_w, foT, 1024,1024, 1, 0,0, 0,0);
    // projections (Q pre-scaled by 1/sqrt(hd) = 1/8)
    gemm_bt<true,false><<<dim3(16,64), blk, 0, stream>>>(query,  WqT, Wq_b, Qm, 4096,1024,1024, 0.125f);
    gemm_bt<true,false><<<dim3(16,64), blk, 0, stream>>>(key_in, WkT, Wk_b, Km, 4096,1024,1024, 1.0f);
    gemm_bt<true,false><<<dim3(16,64), blk, 0, stream>>>(value,  WvT, Wv_b, Vm, 4096,1024,1024, 1.0f);
    // per-head V transpose: (s,d) -> (d,s), f16
    transpose_k<u16><<<dim3(1,32,32), blk, 0, stream>>>(Vm, VTm, 1024, 2048, 16,
        2048L*1024, 64, 16L*64*2048, 64L*2048);
    // fused attention (writes attention f32 + context f16)
    attn_k<<<dim3(1024), blk, 0, stream>>>(Qm, Km, VTm, attn, CTX);
    // output projection (f32 out + f32 bias)
    gemm_bt<false,true><<<dim3(16,64), blk, 0, stream>>>(CTX, foT, fo_b, out, 4096,1024,1024, 1.0f);
}